// Round 5
// baseline (158.033 us; speedup 1.0000x reference)
//
#include <hip/hip_runtime.h>
#include <hip/hip_bf16.h>
#include <cstdint>
#include <cstddef>

#define DEV static __device__ __forceinline__

typedef __bf16 bf16x8 __attribute__((ext_vector_type(8)));
typedef float f32x4 __attribute__((ext_vector_type(4)));
typedef unsigned short u16;

static constexpr int BATCH = 2, SEQ = 2048, DM = 1024, NH = 16, DH = 64;
static constexpr int Kdim = 1024;
static constexpr int BS = BATCH * SEQ;  // 4096

DEV u16 f2b(float f) {  // f32 -> bf16 RNE
  uint32_t u = __builtin_bit_cast(uint32_t, f);
  u += 0x7FFFu + ((u >> 16) & 1u);
  return (u16)(u >> 16);
}

DEV void gload_lds16(const void* g, void* l) {
  __builtin_amdgcn_global_load_lds((const __attribute__((address_space(1))) void*)g,
                                   (__attribute__((address_space(3))) void*)l, 16, 0, 0);
}

// ---------------- fused cast f32 -> bf16 (x + 4 weights) + RoPE cos/sin table ----------------
__global__ __launch_bounds__(256) void cast_all(const float* __restrict__ x,
    const float* __restrict__ wq, const float* __restrict__ wk,
    const float* __restrict__ wv, const float* __restrict__ wo,
    const int* __restrict__ pos,
    u16* __restrict__ xb, u16* __restrict__ wqb, u16* __restrict__ wkb,
    u16* __restrict__ wvb, u16* __restrict__ wob, float2* __restrict__ tab) {
  const int NX = (BATCH * SEQ * DM) / 4;  // 2097152
  const int NW = (DM * DM) / 4;           // 262144 = 1<<18
  const int NT = SEQ * 32;                // 65536 table entries
  int i = blockIdx.x * blockDim.x + threadIdx.x;
  const int stride = gridDim.x * blockDim.x;
  for (; i < NX + 4 * NW + NT; i += stride) {
    if (i < NX + 4 * NW) {
      const float* src; u16* dst; int off;
      if (i < NX) { src = x; dst = xb; off = i; }
      else {
        const int j = i - NX, seg = j >> 18;
        off = j & (NW - 1);
        src = seg == 0 ? wq : seg == 1 ? wk : seg == 2 ? wv : wo;
        dst = seg == 0 ? wqb : seg == 1 ? wkb : seg == 2 ? wvb : wob;
      }
      float4 v = ((const float4*)src)[off];
      ushort4 o;
      o.x = f2b(v.x); o.y = f2b(v.y); o.z = f2b(v.z); o.w = f2b(v.w);
      ((ushort4*)dst)[off] = o;
    } else {
      const int t = i - NX - 4 * NW;
      const int s = t >> 5, j = t & 31;
      // theta^(-j/32) = 2^(-j*log2(1e4)/32)
      const float ang = (float)pos[s] * exp2f((float)j * -0.4152410118609203f);
      float sn, cs;
      sincosf(ang, &sn, &cs);
      tab[t] = make_float2(cs, sn);
    }
  }
}

// ---------------- GEMM core: C[m0.., n0..] = A[M,1024] * B[N,1024]^T ----------------
// 128xBN tile, BK=32, 4 waves (2x2), 16x16x32 bf16 MFMA, double-buffered
// global_load_lds staging (prefetch-before-compute, 1 barrier/K-step).
// ROPE: 0=none, 1=Q (rotate + 0.125*log2e scale), 2=K (rotate only).
template <int BN, bool OUTF32, int ROPE>
DEV void gemm_core(const u16* __restrict__ A, const u16* __restrict__ Bm,
                   void* __restrict__ Cout, int ldC, int m0, int n0,
                   u16* __restrict__ As, u16* __restrict__ Bs,
                   const float2* __restrict__ tab) {
  const int tid = threadIdx.x;
  const int lane = tid & 63, wid = tid >> 6;
  const int wr = (wid >> 1) * 64, wc = (wid & 1) * (BN / 2);
  const int frow = lane & 15, fgrp = lane >> 4;
  constexpr int NF = BN / 32;  // n-frags per wave
  constexpr int BSZ = BN * 32; // Bs elements per buffer
  f32x4 acc[4][NF] = {};

  const int c0 = tid, c1 = tid + 256;
  const int ra0 = c0 >> 2, sa0 = (c0 & 3) ^ (ra0 & 3);
  const int ra1 = c1 >> 2, sa1 = (c1 & 3) ^ (ra1 & 3);
  const size_t gA0 = (size_t)(m0 + ra0) * Kdim + sa0 * 8;
  const size_t gA1 = (size_t)(m0 + ra1) * Kdim + sa1 * 8;
  const size_t gB0 = (size_t)(n0 + ra0) * Kdim + sa0 * 8;
  const size_t gB1 = (size_t)(n0 + ra1) * Kdim + sa1 * 8;

#define GSTAGE(bufi, kofs)                                                      \
  do {                                                                          \
    gload_lds16(A + gA0 + (kofs), As + (bufi) * 4096 + wid * 512);              \
    gload_lds16(A + gA1 + (kofs), As + (bufi) * 4096 + wid * 512 + 2048);       \
    gload_lds16(Bm + gB0 + (kofs), Bs + (bufi) * BSZ + wid * 512);              \
    if (BN == 128)                                                              \
      gload_lds16(Bm + gB1 + (kofs), Bs + (bufi) * BSZ + wid * 512 + 2048);     \
  } while (0)

  GSTAGE(0, 0);
  for (int kt = 0; kt < Kdim / 32; ++kt) {
    const int buf = kt & 1;
    __syncthreads();  // drains previous stage; protects buffer reuse
    if (kt + 1 < Kdim / 32) GSTAGE(buf ^ 1, (kt + 1) * 32);
    bf16x8 af[4], bfr[NF];
#pragma unroll
    for (int i = 0; i < 4; ++i) {
      const int ra = wr + i * 16 + frow;
      af[i] = *(const bf16x8*)((const char*)(As + buf * 4096) + ra * 64 + ((fgrp ^ (ra & 3)) * 16));
    }
#pragma unroll
    for (int f = 0; f < NF; ++f) {
      const int rb = wc + f * 16 + frow;
      bfr[f] = *(const bf16x8*)((const char*)(Bs + buf * BSZ) + rb * 64 + ((fgrp ^ (rb & 3)) * 16));
    }
#pragma unroll
    for (int mi = 0; mi < 4; ++mi)
#pragma unroll
      for (int f = 0; f < NF; ++f)
        acc[mi][f] = __builtin_amdgcn_mfma_f32_16x16x32_bf16(af[mi], bfr[f], acc[mi][f], 0, 0, 0);
  }
#undef GSTAGE

  const int colb = n0 + wc + frow;
  const int rowb = m0 + wr + fgrp * 4;
  if (ROPE) {  // fused RoPE: pair (col even, col+1 odd) lives in lanes frow, frow^1
#pragma unroll
    for (int mi = 0; mi < 4; ++mi)
#pragma unroll
      for (int f = 0; f < NF; ++f) {
        const int col = colb + f * 16;
        const int j = (col & 63) >> 1;
#pragma unroll
        for (int r = 0; r < 4; ++r) {
          const float v = acc[mi][f][r];
          const float partner = __shfl_xor(v, 1);
          const int row = rowb + mi * 16 + r;
          const float2 cs_ = tab[(row & (SEQ - 1)) * 32 + j];
          float outv = (col & 1) ? fmaf(cs_.y, partner, cs_.x * v)
                                 : fmaf(cs_.x, v, -cs_.y * partner);
          if (ROPE == 1) outv *= 0.18033688011112043f;  // (1/8)*log2(e)
          acc[mi][f][r] = outv;
        }
      }
  }
#pragma unroll
  for (int mi = 0; mi < 4; ++mi)
#pragma unroll
    for (int f = 0; f < NF; ++f)
#pragma unroll
      for (int r = 0; r < 4; ++r) {
        const int row = rowb + mi * 16 + r;
        const int col = colb + f * 16;
        const float v = acc[mi][f][r];
        if (OUTF32) ((float*)Cout)[(size_t)row * ldC + col] = v;
        else        ((u16*)Cout)[(size_t)row * ldC + col] = f2b(v);
      }
}

// z=0: Q = rope(X*Wq^T)*scale; z=1: K = rope(X*Wk^T); z=2: V^T = Wv*X^T (1024x4096)
__global__ __launch_bounds__(256) void gemm_qkvt(const u16* __restrict__ xb,
    const u16* __restrict__ wq, const u16* __restrict__ wk, const u16* __restrict__ wv,
    u16* __restrict__ Qb, u16* __restrict__ Kb, u16* __restrict__ Vtb,
    const float2* __restrict__ tab) {
  __shared__ u16 As[2][4096], Bs[2][4096];
  const int i = blockIdx.x, z = blockIdx.z;
  if (z == 0)
    gemm_core<128, false, 1>(xb, wq, Qb, DM, (i >> 3) * 128, (i & 7) * 128, &As[0][0], &Bs[0][0], tab);
  else if (z == 1)
    gemm_core<128, false, 2>(xb, wk, Kb, DM, (i >> 3) * 128, (i & 7) * 128, &As[0][0], &Bs[0][0], tab);
  else
    gemm_core<128, false, 0>(wv, xb, Vtb, BS, (i >> 5) * 128, (i & 31) * 128, &As[0][0], &Bs[0][0], nullptr);
}

__global__ __launch_bounds__(256) void gemm_o(const u16* __restrict__ attb,
                                              const u16* __restrict__ wob,
                                              float* __restrict__ out) {
  __shared__ u16 As[2][4096], Bs[2][2048];
  gemm_core<64, true, 0>(attb, wob, out, DM, blockIdx.y * 128, blockIdx.x * 64,
                         &As[0][0], &Bs[0][0], nullptr);
}

// ---------------- fused causal flash attention ----------------
// grid (32, 32): qt = 31 - blockIdx.x (heavy-first LPT). 256 threads = 4 waves;
// wave w owns q rows [w*16, w*16+16). Swapped QK^T puts S[q=frow][k] lane-local.
// exp2-domain softmax (log2e folded into Q), defer-max rescale (THR=8).
// LDS 40KB -> 4 blocks/CU: Q-tile LDS unioned with per-wave P staging.
__global__ __launch_bounds__(256) void attn_kernel(const u16* __restrict__ Qb,
                                                   const u16* __restrict__ Kb,
                                                   const u16* __restrict__ Vtb,
                                                   u16* __restrict__ attb) {
  __shared__ u16 QPs[4096];            // Q tile (read once) / per-wave P staging
  __shared__ u16 Ks[2][4096], Vt[2][4096];
  const int tid = threadIdx.x, lane = tid & 63, wid = tid >> 6;
  const int qt = 31 - (int)blockIdx.x;
  const int bh = blockIdx.y;
  const int b = bh >> 4, h = bh & 15;
  const int q0 = qt * 64;
  const size_t base_bh = ((size_t)b * SEQ) * DM + h * DH;
  const int frow = lane & 15, fgrp = lane >> 4;

  // staging coords: chunk c -> row r=c>>3, swizzled col chunk s8
  const int c0 = tid, c1 = tid + 256;
  const int r0 = c0 >> 3, s80 = (c0 & 7) ^ (r0 & 7);
  const int r1 = c1 >> 3, s81 = (c1 & 7) ^ (r1 & 7);

  const u16* Ksrc0 = Kb + base_bh + (size_t)r0 * DM + s80 * 8;
  const u16* Ksrc1 = Kb + base_bh + (size_t)r1 * DM + s81 * 8;
  const u16* Vsrc0 = Vtb + (size_t)(h * DH + r0) * BS + (size_t)b * SEQ + s80 * 8;
  const u16* Vsrc1 = Vtb + (size_t)(h * DH + r1) * BS + (size_t)b * SEQ + s81 * 8;

  const int qrow = wid * 16 + frow;

  // prologue: stage Q + (K, V^T) tile 0
  gload_lds16(Qb + base_bh + (size_t)(q0 + r0) * DM + s80 * 8, (char*)QPs + wid * 1024);
  gload_lds16(Qb + base_bh + (size_t)(q0 + r1) * DM + s81 * 8, (char*)QPs + wid * 1024 + 4096);
  gload_lds16(Ksrc0, (char*)Ks[0] + wid * 1024);
  gload_lds16(Ksrc1, (char*)Ks[0] + wid * 1024 + 4096);
  gload_lds16(Vsrc0, (char*)Vt[0] + wid * 1024);
  gload_lds16(Vsrc1, (char*)Vt[0] + wid * 1024 + 4096);
  __syncthreads();

  bf16x8 qf[2];
#pragma unroll
  for (int ks = 0; ks < 2; ++ks) {
    const int byte = (qrow * 128 + ks * 64 + fgrp * 16) ^ ((qrow & 7) << 4);
    qf[ks] = *(const bf16x8*)((const char*)QPs + byte);
  }

  float m_sc = -1e30f, l_sc = 0.f;
  f32x4 accO[4] = {};
  int cur = 0;

  for (int kt = 0; kt <= qt; ++kt) {
    if (kt < qt) {  // prefetch next tile (overlaps compute; drained by end barrier)
      const size_t kvn = (size_t)(kt + 1) * 64;
      gload_lds16(Ksrc0 + kvn * DM, (char*)Ks[cur ^ 1] + wid * 1024);
      gload_lds16(Ksrc1 + kvn * DM, (char*)Ks[cur ^ 1] + wid * 1024 + 4096);
      gload_lds16(Vsrc0 + kvn, (char*)Vt[cur ^ 1] + wid * 1024);
      gload_lds16(Vsrc1 + kvn, (char*)Vt[cur ^ 1] + wid * 1024 + 4096);
    }

    // S^T tiles: sc[tc][r] = S'[q=frow][k = tc*16 + fgrp*4 + r]  (log2e-scaled)
    f32x4 sc[4] = {};
#pragma unroll
    for (int tc = 0; tc < 4; ++tc) {
      const int krow = tc * 16 + frow;
#pragma unroll
      for (int ks = 0; ks < 2; ++ks) {
        const int byte = (krow * 128 + ks * 64 + fgrp * 16) ^ ((krow & 7) << 4);
        const bf16x8 kf = *(const bf16x8*)((const char*)Ks[cur] + byte);
        sc[tc] = __builtin_amdgcn_mfma_f32_16x16x32_bf16(kf, qf[ks], sc[tc], 0, 0, 0);
      }
    }
    if (kt == qt) {  // causal mask on diagonal tile
#pragma unroll
      for (int tc = 0; tc < 4; ++tc)
#pragma unroll
        for (int r = 0; r < 4; ++r)
          if (tc * 16 + fgrp * 4 + r > qrow) sc[tc][r] = -1e30f;
    }

    // online softmax (exp2 domain), defer-max with THR=8
    float vmax = fmaxf(fmaxf(sc[0][0], sc[0][1]), fmaxf(sc[0][2], sc[0][3]));
#pragma unroll
    for (int tc = 1; tc < 4; ++tc)
      vmax = fmaxf(vmax, fmaxf(fmaxf(sc[tc][0], sc[tc][1]), fmaxf(sc[tc][2], sc[tc][3])));
    vmax = fmaxf(vmax, __shfl_xor(vmax, 16));
    vmax = fmaxf(vmax, __shfl_xor(vmax, 32));
    if (__any(vmax - m_sc > 8.f)) {  // rescale path (rare after warm-up)
      const float mnew = fmaxf(m_sc, vmax);
      const float scl = exp2f(m_sc - mnew);
      m_sc = mnew;
      l_sc *= scl;
#pragma unroll
      for (int r = 0; r < 4; ++r) {
        const float s = __shfl(scl, fgrp * 4 + r, 64);
#pragma unroll
        for (int te = 0; te < 4; ++te) accO[te][r] *= s;
      }
    }
    float rsum = 0.f;
#pragma unroll
    for (int tc = 0; tc < 4; ++tc)
#pragma unroll
      for (int r = 0; r < 4; ++r) {
        const float p = exp2f(sc[tc][r] - m_sc);
        sc[tc][r] = p;
        rsum += p;
      }
    rsum += __shfl_xor(rsum, 16);
    rsum += __shfl_xor(rsum, 32);
    l_sc += rsum;

    // P -> LDS (per-wave region of QPs): native casts -> v_cvt_pk_bf16_f32
    u16* Pw = QPs + wid * 1024;
#pragma unroll
    for (int tc = 0; tc < 4; ++tc) {
      union { __bf16 b[4]; uint2 u; } cv;
      cv.b[0] = (__bf16)sc[tc][0]; cv.b[1] = (__bf16)sc[tc][1];
      cv.b[2] = (__bf16)sc[tc][2]; cv.b[3] = (__bf16)sc[tc][3];
      const int byte = (frow * 128 + tc * 32 + fgrp * 8) ^ ((frow & 7) << 4);
      *(uint2*)((char*)Pw + byte) = cv.u;
    }
    bf16x8 pf[2];
#pragma unroll
    for (int ks = 0; ks < 2; ++ks) {
      const int byte = (frow * 128 + ks * 64 + fgrp * 16) ^ ((frow & 7) << 4);
      pf[ks] = *(const bf16x8*)((const char*)Pw + byte);
    }
#pragma unroll
    for (int te = 0; te < 4; ++te) {
      const int vrow = te * 16 + frow;  // V^T row = head-dim e
#pragma unroll
      for (int ks = 0; ks < 2; ++ks) {
        const int byte = (vrow * 128 + ks * 64 + fgrp * 16) ^ ((vrow & 7) << 4);
        const bf16x8 vf = *(const bf16x8*)((const char*)Vt[cur] + byte);
        accO[te] = __builtin_amdgcn_mfma_f32_16x16x32_bf16(pf[ks], vf, accO[te], 0, 0, 0);
      }
    }
    __syncthreads();  // drains staged loads; protects buffer swap
    cur ^= 1;
  }

  // epilogue: O /= l, write att (b, s, h, e) as bf16
  float lfin[4];
#pragma unroll
  for (int r = 0; r < 4; ++r) lfin[r] = __shfl(l_sc, fgrp * 4 + r, 64);
#pragma unroll
  for (int te = 0; te < 4; ++te)
#pragma unroll
    for (int r = 0; r < 4; ++r) {
      const float o = accO[te][r] / lfin[r];
      const int row = q0 + wid * 16 + fgrp * 4 + r;
      const int col = te * 16 + frow;
      attb[base_bh + (size_t)row * DM + col] = f2b(o);
    }
}

extern "C" void kernel_launch(void* const* d_in, const int* in_sizes, int n_in,
                              void* d_out, int out_size, void* d_ws, size_t ws_size,
                              hipStream_t stream) {
  const float* x  = (const float*)d_in[0];
  const float* wq = (const float*)d_in[1];
  const float* wk = (const float*)d_in[2];
  const float* wv = (const float*)d_in[3];
  const float* wo = (const float*)d_in[4];
  const int* pos  = (const int*)d_in[5];
  float* out = (float*)d_out;
  (void)in_sizes; (void)n_in; (void)out_size; (void)ws_size;

  char* ws = (char*)d_ws;
  const size_t MB = 1024 * 1024;
  u16* xb   = (u16*)(ws);
  u16* wqb  = (u16*)(ws + 8 * MB);
  u16* wkb  = (u16*)(ws + 10 * MB);
  u16* wvb  = (u16*)(ws + 12 * MB);
  u16* wob  = (u16*)(ws + 14 * MB);
  u16* Qb   = (u16*)(ws + 16 * MB);
  u16* Kb   = (u16*)(ws + 24 * MB);
  u16* Vtb  = (u16*)(ws + 32 * MB);   // V^T: [1024][4096]
  u16* attb = (u16*)(ws + 40 * MB);
  // RoPE table aliases the attb region: written by cast_all, read by gemm_qkvt,
  // then attn overwrites it with attb (strictly later in stream order).
  float2* tab = (float2*)(ws + 40 * MB);

  cast_all<<<2048, 256, 0, stream>>>(x, wq, wk, wv, wo, pos, xb, wqb, wkb, wvb, wob, tab);
  gemm_qkvt<<<dim3(256, 1, 3), 256, 0, stream>>>(xb, wqb, wkb, wvb, Qb, Kb, Vtb, tab);
  attn_kernel<<<dim3(32, 32), 256, 0, stream>>>(Qb, Kb, Vtb, attb);
  gemm_o<<<dim3(16, 32), 256, 0, stream>>>(attb, wob, out);
}

// Round 6
// 132.767 us; speedup vs baseline: 1.1903x; 1.1903x over previous
//
#include <hip/hip_runtime.h>
#include <hip/hip_bf16.h>
#include <cstdint>
#include <cstddef>

#define DEV static __device__ __forceinline__

typedef __bf16 bf16x8 __attribute__((ext_vector_type(8)));
typedef float f32x4 __attribute__((ext_vector_type(4)));
typedef unsigned short u16;

static constexpr int BATCH = 2, SEQ = 2048, DM = 1024, NH = 16, DH = 64;
static constexpr int Kdim = 1024;
static constexpr int BS = BATCH * SEQ;  // 4096

DEV u16 f2b(float f) {  // f32 -> bf16 RNE
  uint32_t u = __builtin_bit_cast(uint32_t, f);
  u += 0x7FFFu + ((u >> 16) & 1u);
  return (u16)(u >> 16);
}

DEV void gload_lds16(const void* g, void* l) {
  __builtin_amdgcn_global_load_lds((const __attribute__((address_space(1))) void*)g,
                                   (__attribute__((address_space(3))) void*)l, 16, 0, 0);
}

// ---------------- fused cast f32 -> bf16 (x + 4 weights) + RoPE cos/sin table ----------------
__global__ __launch_bounds__(256) void cast_all(const float* __restrict__ x,
    const float* __restrict__ wq, const float* __restrict__ wk,
    const float* __restrict__ wv, const float* __restrict__ wo,
    const int* __restrict__ pos,
    u16* __restrict__ xb, u16* __restrict__ wqb, u16* __restrict__ wkb,
    u16* __restrict__ wvb, u16* __restrict__ wob, float2* __restrict__ tab) {
  const int NX = (BATCH * SEQ * DM) / 4;  // 2097152
  const int NW = (DM * DM) / 4;           // 262144 = 1<<18
  const int NT = SEQ * 32;                // 65536 table entries
  int i = blockIdx.x * blockDim.x + threadIdx.x;
  const int stride = gridDim.x * blockDim.x;
  for (; i < NX + 4 * NW + NT; i += stride) {
    if (i < NX + 4 * NW) {
      const float* src; u16* dst; int off;
      if (i < NX) { src = x; dst = xb; off = i; }
      else {
        const int j = i - NX, seg = j >> 18;
        off = j & (NW - 1);
        src = seg == 0 ? wq : seg == 1 ? wk : seg == 2 ? wv : wo;
        dst = seg == 0 ? wqb : seg == 1 ? wkb : seg == 2 ? wvb : wob;
      }
      float4 v = ((const float4*)src)[off];
      ushort4 o;
      o.x = f2b(v.x); o.y = f2b(v.y); o.z = f2b(v.z); o.w = f2b(v.w);
      ((ushort4*)dst)[off] = o;
    } else {
      const int t = i - NX - 4 * NW;
      const int s = t >> 5, j = t & 31;
      // theta^(-j/32) = 2^(-j*log2(1e4)/32)
      const float ang = (float)pos[s] * exp2f((float)j * -0.4152410118609203f);
      float sn, cs;
      sincosf(ang, &sn, &cs);
      tab[t] = make_float2(cs, sn);
    }
  }
}

// ---------------- GEMM core: C[m0.., n0..] = A[M,1024] * B[N,1024]^T ----------------
// 128xBN tile, BK=32, 4 waves (2x2), 16x16x32 bf16 MFMA, double-buffered
// global_load_lds staging (prefetch-before-compute, 1 barrier/K-step).
// ROPE: 0=none, 1=Q (rotate + 0.125*log2e scale), 2=K (rotate only).
template <int BN, bool OUTF32, int ROPE>
DEV void gemm_core(const u16* __restrict__ A, const u16* __restrict__ Bm,
                   void* __restrict__ Cout, int ldC, int m0, int n0,
                   u16* __restrict__ As, u16* __restrict__ Bs,
                   const float2* __restrict__ tab) {
  const int tid = threadIdx.x;
  const int lane = tid & 63, wid = tid >> 6;
  const int wr = (wid >> 1) * 64, wc = (wid & 1) * (BN / 2);
  const int frow = lane & 15, fgrp = lane >> 4;
  constexpr int NF = BN / 32;  // n-frags per wave
  constexpr int BSZ = BN * 32; // Bs elements per buffer
  f32x4 acc[4][NF] = {};

  const int c0 = tid, c1 = tid + 256;
  const int ra0 = c0 >> 2, sa0 = (c0 & 3) ^ (ra0 & 3);
  const int ra1 = c1 >> 2, sa1 = (c1 & 3) ^ (ra1 & 3);
  const size_t gA0 = (size_t)(m0 + ra0) * Kdim + sa0 * 8;
  const size_t gA1 = (size_t)(m0 + ra1) * Kdim + sa1 * 8;
  const size_t gB0 = (size_t)(n0 + ra0) * Kdim + sa0 * 8;
  const size_t gB1 = (size_t)(n0 + ra1) * Kdim + sa1 * 8;

#define GSTAGE(bufi, kofs)                                                      \
  do {                                                                          \
    gload_lds16(A + gA0 + (kofs), As + (bufi) * 4096 + wid * 512);              \
    gload_lds16(A + gA1 + (kofs), As + (bufi) * 4096 + wid * 512 + 2048);       \
    gload_lds16(Bm + gB0 + (kofs), Bs + (bufi) * BSZ + wid * 512);              \
    if (BN == 128)                                                              \
      gload_lds16(Bm + gB1 + (kofs), Bs + (bufi) * BSZ + wid * 512 + 2048);     \
  } while (0)

  GSTAGE(0, 0);
  for (int kt = 0; kt < Kdim / 32; ++kt) {
    const int buf = kt & 1;
    __syncthreads();  // drains previous stage; protects buffer reuse
    if (kt + 1 < Kdim / 32) GSTAGE(buf ^ 1, (kt + 1) * 32);
    bf16x8 af[4], bfr[NF];
#pragma unroll
    for (int i = 0; i < 4; ++i) {
      const int ra = wr + i * 16 + frow;
      af[i] = *(const bf16x8*)((const char*)(As + buf * 4096) + ra * 64 + ((fgrp ^ (ra & 3)) * 16));
    }
#pragma unroll
    for (int f = 0; f < NF; ++f) {
      const int rb = wc + f * 16 + frow;
      bfr[f] = *(const bf16x8*)((const char*)(Bs + buf * BSZ) + rb * 64 + ((fgrp ^ (rb & 3)) * 16));
    }
#pragma unroll
    for (int mi = 0; mi < 4; ++mi)
#pragma unroll
      for (int f = 0; f < NF; ++f)
        acc[mi][f] = __builtin_amdgcn_mfma_f32_16x16x32_bf16(af[mi], bfr[f], acc[mi][f], 0, 0, 0);
  }
#undef GSTAGE

  const int colb = n0 + wc + frow;
  const int rowb = m0 + wr + fgrp * 4;
  if (ROPE) {  // fused RoPE: pair (col even, col+1 odd) lives in lanes frow, frow^1
#pragma unroll
    for (int mi = 0; mi < 4; ++mi)
#pragma unroll
      for (int f = 0; f < NF; ++f) {
        const int col = colb + f * 16;
        const int j = (col & 63) >> 1;
#pragma unroll
        for (int r = 0; r < 4; ++r) {
          const float v = acc[mi][f][r];
          const float partner = __shfl_xor(v, 1);
          const int row = rowb + mi * 16 + r;
          const float2 cs_ = tab[(row & (SEQ - 1)) * 32 + j];
          float outv = (col & 1) ? fmaf(cs_.y, partner, cs_.x * v)
                                 : fmaf(cs_.x, v, -cs_.y * partner);
          if (ROPE == 1) outv *= 0.18033688011112043f;  // (1/8)*log2(e)
          acc[mi][f][r] = outv;
        }
      }
  }
#pragma unroll
  for (int mi = 0; mi < 4; ++mi)
#pragma unroll
    for (int f = 0; f < NF; ++f)
#pragma unroll
      for (int r = 0; r < 4; ++r) {
        const int row = rowb + mi * 16 + r;
        const int col = colb + f * 16;
        const float v = acc[mi][f][r];
        if (OUTF32) ((float*)Cout)[(size_t)row * ldC + col] = v;
        else        ((u16*)Cout)[(size_t)row * ldC + col] = f2b(v);
      }
}

// z=0: Q = rope(X*Wq^T)*scale; z=1: K = rope(X*Wk^T); z=2: V^T = Wv*X^T (1024x4096)
__global__ __launch_bounds__(256) void gemm_qkvt(const u16* __restrict__ xb,
    const u16* __restrict__ wq, const u16* __restrict__ wk, const u16* __restrict__ wv,
    u16* __restrict__ Qb, u16* __restrict__ Kb, u16* __restrict__ Vtb,
    const float2* __restrict__ tab) {
  __shared__ u16 As[2][4096], Bs[2][4096];
  const int i = blockIdx.x, z = blockIdx.z;
  if (z == 0)
    gemm_core<128, false, 1>(xb, wq, Qb, DM, (i >> 3) * 128, (i & 7) * 128, &As[0][0], &Bs[0][0], tab);
  else if (z == 1)
    gemm_core<128, false, 2>(xb, wk, Kb, DM, (i >> 3) * 128, (i & 7) * 128, &As[0][0], &Bs[0][0], tab);
  else
    gemm_core<128, false, 0>(wv, xb, Vtb, BS, (i >> 5) * 128, (i & 31) * 128, &As[0][0], &Bs[0][0], nullptr);
}

__global__ __launch_bounds__(256) void gemm_o(const u16* __restrict__ attb,
                                              const u16* __restrict__ wob,
                                              float* __restrict__ out) {
  __shared__ u16 As[2][4096], Bs[2][2048];
  gemm_core<64, true, 0>(attb, wob, out, DM, blockIdx.y * 128, blockIdx.x * 64,
                         &As[0][0], &Bs[0][0], nullptr);
}

// ---------------- fused causal flash attention ----------------
// grid (16, 32): block x handles q-tiles {31-x, x} — exactly 33 KV iters per
// block (perfectly balanced; LPT degenerates when grid <= resident capacity).
// 256 threads = 4 waves; wave w owns q rows [w*16, w*16+16). Swapped QK^T puts
// S[q=frow][k] lane-local. exp2-domain softmax (log2e folded into Q at proj),
// defer-max rescale (THR=8). LDS 40KB: Q-tile LDS unioned with per-wave P.
__global__ __launch_bounds__(256) void attn_kernel(const u16* __restrict__ Qb,
                                                   const u16* __restrict__ Kb,
                                                   const u16* __restrict__ Vtb,
                                                   u16* __restrict__ attb) {
  __shared__ u16 QPs[4096];            // Q tile (read once per phase) / per-wave P staging
  __shared__ u16 Ks[2][4096], Vt[2][4096];
  const int tid = threadIdx.x, lane = tid & 63, wid = tid >> 6;
  const int bh = blockIdx.y;
  const int b = bh >> 4, h = bh & 15;
  const size_t base_bh = ((size_t)b * SEQ) * DM + h * DH;
  const int frow = lane & 15, fgrp = lane >> 4;

  // staging coords: chunk c -> row r=c>>3, swizzled col chunk s8
  const int c0 = tid, c1 = tid + 256;
  const int r0 = c0 >> 3, s80 = (c0 & 7) ^ (r0 & 7);
  const int r1 = c1 >> 3, s81 = (c1 & 7) ^ (r1 & 7);

  const u16* Ksrc0 = Kb + base_bh + (size_t)r0 * DM + s80 * 8;
  const u16* Ksrc1 = Kb + base_bh + (size_t)r1 * DM + s81 * 8;
  const u16* Vsrc0 = Vtb + (size_t)(h * DH + r0) * BS + (size_t)b * SEQ + s80 * 8;
  const u16* Vsrc1 = Vtb + (size_t)(h * DH + r1) * BS + (size_t)b * SEQ + s81 * 8;

  const int qrow = wid * 16 + frow;

#pragma unroll 1
  for (int phase = 0; phase < 2; ++phase) {
    const int qt = phase ? (int)blockIdx.x : 31 - (int)blockIdx.x;
    const int q0 = qt * 64;

    // prologue: stage Q + (K, V^T) tile 0  (all LDS readers passed last barrier)
    gload_lds16(Qb + base_bh + (size_t)(q0 + r0) * DM + s80 * 8, (char*)QPs + wid * 1024);
    gload_lds16(Qb + base_bh + (size_t)(q0 + r1) * DM + s81 * 8, (char*)QPs + wid * 1024 + 4096);
    gload_lds16(Ksrc0, (char*)Ks[0] + wid * 1024);
    gload_lds16(Ksrc1, (char*)Ks[0] + wid * 1024 + 4096);
    gload_lds16(Vsrc0, (char*)Vt[0] + wid * 1024);
    gload_lds16(Vsrc1, (char*)Vt[0] + wid * 1024 + 4096);
    __syncthreads();

    bf16x8 qf[2];
#pragma unroll
    for (int ks = 0; ks < 2; ++ks) {
      const int byte = (qrow * 128 + ks * 64 + fgrp * 16) ^ ((qrow & 7) << 4);
      qf[ks] = *(const bf16x8*)((const char*)QPs + byte);
    }

    float m_sc = -1e30f, l_sc = 0.f;
    f32x4 accO[4] = {};
    int cur = 0;

    for (int kt = 0; kt <= qt; ++kt) {
      if (kt < qt) {  // prefetch next tile (overlaps compute; drained by end barrier)
        const size_t kvn = (size_t)(kt + 1) * 64;
        gload_lds16(Ksrc0 + kvn * DM, (char*)Ks[cur ^ 1] + wid * 1024);
        gload_lds16(Ksrc1 + kvn * DM, (char*)Ks[cur ^ 1] + wid * 1024 + 4096);
        gload_lds16(Vsrc0 + kvn, (char*)Vt[cur ^ 1] + wid * 1024);
        gload_lds16(Vsrc1 + kvn, (char*)Vt[cur ^ 1] + wid * 1024 + 4096);
      }

      // S^T tiles: sc[tc][r] = S'[q=frow][k = tc*16 + fgrp*4 + r]  (log2e-scaled)
      f32x4 sc[4] = {};
#pragma unroll
      for (int tc = 0; tc < 4; ++tc) {
        const int krow = tc * 16 + frow;
#pragma unroll
        for (int ks = 0; ks < 2; ++ks) {
          const int byte = (krow * 128 + ks * 64 + fgrp * 16) ^ ((krow & 7) << 4);
          const bf16x8 kf = *(const bf16x8*)((const char*)Ks[cur] + byte);
          sc[tc] = __builtin_amdgcn_mfma_f32_16x16x32_bf16(kf, qf[ks], sc[tc], 0, 0, 0);
        }
      }
      if (kt == qt) {  // causal mask on diagonal tile
#pragma unroll
        for (int tc = 0; tc < 4; ++tc)
#pragma unroll
          for (int r = 0; r < 4; ++r)
            if (tc * 16 + fgrp * 4 + r > qrow) sc[tc][r] = -1e30f;
      }

      // online softmax (exp2 domain), defer-max with THR=8
      float vmax = fmaxf(fmaxf(sc[0][0], sc[0][1]), fmaxf(sc[0][2], sc[0][3]));
#pragma unroll
      for (int tc = 1; tc < 4; ++tc)
        vmax = fmaxf(vmax, fmaxf(fmaxf(sc[tc][0], sc[tc][1]), fmaxf(sc[tc][2], sc[tc][3])));
      vmax = fmaxf(vmax, __shfl_xor(vmax, 16));
      vmax = fmaxf(vmax, __shfl_xor(vmax, 32));
      if (__any(vmax - m_sc > 8.f)) {  // rescale path (rare after warm-up)
        const float mnew = fmaxf(m_sc, vmax);
        const float scl = exp2f(m_sc - mnew);
        m_sc = mnew;
        l_sc *= scl;
#pragma unroll
        for (int r = 0; r < 4; ++r) {
          const float s = __shfl(scl, fgrp * 4 + r, 64);
#pragma unroll
          for (int te = 0; te < 4; ++te) accO[te][r] *= s;
        }
      }
      float rsum = 0.f;
#pragma unroll
      for (int tc = 0; tc < 4; ++tc)
#pragma unroll
        for (int r = 0; r < 4; ++r) {
          const float p = exp2f(sc[tc][r] - m_sc);
          sc[tc][r] = p;
          rsum += p;
        }
      rsum += __shfl_xor(rsum, 16);
      rsum += __shfl_xor(rsum, 32);
      l_sc += rsum;

      // P -> LDS (per-wave region of QPs): native casts -> v_cvt_pk_bf16_f32
      u16* Pw = QPs + wid * 1024;
#pragma unroll
      for (int tc = 0; tc < 4; ++tc) {
        union { __bf16 b[4]; uint2 u; } cv;
        cv.b[0] = (__bf16)sc[tc][0]; cv.b[1] = (__bf16)sc[tc][1];
        cv.b[2] = (__bf16)sc[tc][2]; cv.b[3] = (__bf16)sc[tc][3];
        const int byte = (frow * 128 + tc * 32 + fgrp * 8) ^ ((frow & 7) << 4);
        *(uint2*)((char*)Pw + byte) = cv.u;
      }
      bf16x8 pf[2];
#pragma unroll
      for (int ks = 0; ks < 2; ++ks) {
        const int byte = (frow * 128 + ks * 64 + fgrp * 16) ^ ((frow & 7) << 4);
        pf[ks] = *(const bf16x8*)((const char*)Pw + byte);
      }
#pragma unroll
      for (int te = 0; te < 4; ++te) {
        const int vrow = te * 16 + frow;  // V^T row = head-dim e
#pragma unroll
        for (int ks = 0; ks < 2; ++ks) {
          const int byte = (vrow * 128 + ks * 64 + fgrp * 16) ^ ((vrow & 7) << 4);
          const bf16x8 vf = *(const bf16x8*)((const char*)Vt[cur] + byte);
          accO[te] = __builtin_amdgcn_mfma_f32_16x16x32_bf16(pf[ks], vf, accO[te], 0, 0, 0);
        }
      }
      __syncthreads();  // drains staged loads; protects buffer swap
      cur ^= 1;
    }

    // epilogue: O /= l, write att (b, s, h, e) as bf16
    float lfin[4];
#pragma unroll
    for (int r = 0; r < 4; ++r) lfin[r] = __shfl(l_sc, fgrp * 4 + r, 64);
#pragma unroll
    for (int te = 0; te < 4; ++te)
#pragma unroll
      for (int r = 0; r < 4; ++r) {
        const float o = accO[te][r] / lfin[r];
        const int row = q0 + wid * 16 + fgrp * 4 + r;
        const int col = te * 16 + frow;
        attb[base_bh + (size_t)row * DM + col] = f2b(o);
      }
  }
}

extern "C" void kernel_launch(void* const* d_in, const int* in_sizes, int n_in,
                              void* d_out, int out_size, void* d_ws, size_t ws_size,
                              hipStream_t stream) {
  const float* x  = (const float*)d_in[0];
  const float* wq = (const float*)d_in[1];
  const float* wk = (const float*)d_in[2];
  const float* wv = (const float*)d_in[3];
  const float* wo = (const float*)d_in[4];
  const int* pos  = (const int*)d_in[5];
  float* out = (float*)d_out;
  (void)in_sizes; (void)n_in; (void)out_size; (void)ws_size;

  char* ws = (char*)d_ws;
  const size_t MB = 1024 * 1024;
  u16* xb   = (u16*)(ws);
  u16* wqb  = (u16*)(ws + 8 * MB);
  u16* wkb  = (u16*)(ws + 10 * MB);
  u16* wvb  = (u16*)(ws + 12 * MB);
  u16* wob  = (u16*)(ws + 14 * MB);
  u16* Qb   = (u16*)(ws + 16 * MB);
  u16* Kb   = (u16*)(ws + 24 * MB);
  u16* Vtb  = (u16*)(ws + 32 * MB);   // V^T: [1024][4096]
  u16* attb = (u16*)(ws + 40 * MB);
  // RoPE table aliases the attb region: written by cast_all, read by gemm_qkvt,
  // then attn overwrites it with attb (strictly later in stream order).
  float2* tab = (float2*)(ws + 40 * MB);

  cast_all<<<2048, 256, 0, stream>>>(x, wq, wk, wv, wo, pos, xb, wqb, wkb, wvb, wob, tab);
  gemm_qkvt<<<dim3(256, 1, 3), 256, 0, stream>>>(xb, wqb, wkb, wvb, Qb, Kb, Vtb, tab);
  attn_kernel<<<dim3(16, 32), 256, 0, stream>>>(Qb, Kb, Vtb, attb);
  gemm_o<<<dim3(16, 32), 256, 0, stream>>>(attb, wob, out);
}